// Round 1
// baseline (1610.737 us; speedup 1.0000x reference)
//
#include <hip/hip_runtime.h>
#include <math.h>

// x: [NUM_EDGES, 512] f32, path_len: [NUM_EDGES] i32
// out[e,i] = x[e,i] + (i even ? sin : cos)(path_len[e] * exp(-(i - i%2) * ln(10000)/512))

#define D_MODEL 512
#define BLOCK 128  // 128 threads * 4 floats = 512 columns per row

__global__ __launch_bounds__(BLOCK) void pe_add_kernel(
    const float* __restrict__ x,
    const int* __restrict__ path_len,
    float* __restrict__ out,
    int num_edges)
{
    const int tid = threadIdx.x;       // 0..127
    const int col = tid * 4;           // base column of this thread's float4

    // exponent scale: -ln(10000)/d_model
    const float kscale = -9.210340371976184f / (float)D_MODEL;
    // pair indices for the 4 columns: (col,col), (col+2,col+2)
    const float div0 = expf((float)col * kscale);
    const float div1 = expf((float)(col + 2) * kscale);

    for (int row = blockIdx.x; row < num_edges; row += gridDim.x) {
        const float p = (float)path_len[row];
        float s0, c0, s1, c1;
        sincosf(p * div0, &s0, &c0);
        sincosf(p * div1, &s1, &c1);

        const size_t base = (size_t)row * D_MODEL;
        const float4 xv = reinterpret_cast<const float4*>(x + base)[tid];
        float4 o;
        o.x = xv.x + s0;  // even col  -> sin
        o.y = xv.y + c0;  // odd col   -> cos
        o.z = xv.z + s1;  // even col+2-> sin
        o.w = xv.w + c1;  // odd col+3 -> cos
        reinterpret_cast<float4*>(out + base)[tid] = o;
    }
}

extern "C" void kernel_launch(void* const* d_in, const int* in_sizes, int n_in,
                              void* d_out, int out_size, void* d_ws, size_t ws_size,
                              hipStream_t stream) {
    const float* x = (const float*)d_in[0];
    const int* path_len = (const int*)d_in[1];
    float* out = (float*)d_out;

    const int num_edges = in_sizes[1];  // path_len has one entry per edge

    const int grid = 16384;  // grid-stride over rows; ~30 rows/block
    pe_add_kernel<<<grid, BLOCK, 0, stream>>>(x, path_len, out, num_edges);
}